// Round 2
// baseline (207.501 us; speedup 1.0000x reference)
//
#include <hip/hip_runtime.h>
#include <float.h>

// Chamfer distance, fp32, N=M=16384.
// d(q,t) = |q|^2 + (|t|^2 - 2 q.t). Targets pre-transformed to
// t4 = (-2x,-2y,-2z,|t|^2) so the inner loop is 3 fma + 1 fmin per pair.
// Each block: 64 queries (one per lane), 4 waves each sweep a wave-uniform
// 4096-target slice (scalar-load friendly), LDS 4-way combine, one
// atomicAdd(out) per block. No global min slots, no init kernel.

#define NPTS 16384
constexpr int QPB   = 64;           // queries per block (one per lane)
constexpr int NW    = 4;            // waves per block
constexpr int SLICE = NPTS / NW;    // 4096 targets per wave

__global__ __launch_bounds__(256) void cd_transform(const float* __restrict__ gt,
                                                    const float* __restrict__ gen,
                                                    float4* __restrict__ T4) {
    int i = blockIdx.x * blockDim.x + threadIdx.x;
    if (i >= 2 * NPTS) return;
    const float* p = (i < NPTS) ? (gt + 3 * i) : (gen + 3 * (i - NPTS));
    float x = p[0], y = p[1], z = p[2];
    T4[i] = make_float4(-2.0f * x, -2.0f * y, -2.0f * z,
                        fmaf(x, x, fmaf(y, y, z * z)));
}

__global__ __launch_bounds__(256) void cd_main(const float* __restrict__ gt,
                                               const float* __restrict__ gen,
                                               const float4* __restrict__ T4,
                                               float* __restrict__ out) {
    const int dir = blockIdx.y;                    // 0: gt->gen, 1: gen->gt
    const float* __restrict__ Q = dir ? gen : gt;  // raw queries
    const float4* __restrict__ T = T4 + (dir ? 0 : NPTS);  // transformed targets

    const int lane = threadIdx.x & 63;
    // readfirstlane makes the wave id provably uniform -> target loads can
    // promote to scalar (s_load) since the sweep index is wave-uniform.
    const int wave = __builtin_amdgcn_readfirstlane(threadIdx.x >> 6);

    const int q = blockIdx.x * QPB + lane;
    const float qx = Q[3 * q + 0];
    const float qy = Q[3 * q + 1];
    const float qz = Q[3 * q + 2];

    float m0 = FLT_MAX, m1 = FLT_MAX, m2 = FLT_MAX, m3 = FLT_MAX;
    const int j0 = wave * SLICE;

    for (int j = j0; j < j0 + SLICE; j += 8) {
        const float4 t0 = T[j + 0];
        const float4 t1 = T[j + 1];
        const float4 t2 = T[j + 2];
        const float4 t3 = T[j + 3];
        const float4 t4 = T[j + 4];
        const float4 t5 = T[j + 5];
        const float4 t6 = T[j + 6];
        const float4 t7 = T[j + 7];
        m0 = fminf(m0, fmaf(qx, t0.x, fmaf(qy, t0.y, fmaf(qz, t0.z, t0.w))));
        m1 = fminf(m1, fmaf(qx, t1.x, fmaf(qy, t1.y, fmaf(qz, t1.z, t1.w))));
        m2 = fminf(m2, fmaf(qx, t2.x, fmaf(qy, t2.y, fmaf(qz, t2.z, t2.w))));
        m3 = fminf(m3, fmaf(qx, t3.x, fmaf(qy, t3.y, fmaf(qz, t3.z, t3.w))));
        m0 = fminf(m0, fmaf(qx, t4.x, fmaf(qy, t4.y, fmaf(qz, t4.z, t4.w))));
        m1 = fminf(m1, fmaf(qx, t5.x, fmaf(qy, t5.y, fmaf(qz, t5.z, t5.w))));
        m2 = fminf(m2, fmaf(qx, t6.x, fmaf(qy, t6.y, fmaf(qz, t6.z, t6.w))));
        m3 = fminf(m3, fmaf(qx, t7.x, fmaf(qy, t7.y, fmaf(qz, t7.z, t7.w))));
    }
    const float m = fminf(fminf(m0, m1), fminf(m2, m3));

    __shared__ float part[NW][QPB];
    part[wave][lane] = m;
    __syncthreads();

    if (threadIdx.x < QPB) {   // wave 0; its (qx,qy,qz) match lane's query
        float mm = fminf(fminf(part[0][lane], part[1][lane]),
                         fminf(part[2][lane], part[3][lane]));
        float d = mm + fmaf(qx, qx, fmaf(qy, qy, qz * qz)); // + |q|^2
        #pragma unroll
        for (int off = 32; off > 0; off >>= 1) d += __shfl_down(d, off, 64);
        if (lane == 0) atomicAdd(out, d * (1.0f / (float)NPTS));
    }
}

extern "C" void kernel_launch(void* const* d_in, const int* in_sizes, int n_in,
                              void* d_out, int out_size, void* d_ws, size_t ws_size,
                              hipStream_t stream) {
    const float* gt  = (const float*)d_in[0];
    const float* gen = (const float*)d_in[1];
    float4* T4       = (float4*)d_ws;            // 2*16384*16 = 512 KB
    float* out       = (float*)d_out;

    hipMemsetAsync(out, 0, sizeof(float) * out_size, stream);

    cd_transform<<<(2 * NPTS + 255) / 256, 256, 0, stream>>>(gt, gen, T4);

    dim3 grid(NPTS / QPB, 2);                    // 256 x 2 = 512 blocks
    cd_main<<<grid, 256, 0, stream>>>(gt, gen, T4, out);
}

// Round 3
// 99.575 us; speedup vs baseline: 2.0839x; 2.0839x over previous
//
#include <hip/hip_runtime.h>
#include <float.h>

// Chamfer distance, fp32, N=M=16384.
// d(q,t) = |q|^2 + (|t|^2 - 2 q.t). Targets transformed in-kernel to SoA LDS
// (TX=-2x, TY=-2y, TZ=-2z, TW=|t|^2). Each wave register-caches NQ=16
// wave-uniform queries as packed (q,q) float2 pairs; lanes stream 2 targets
// each per step via ds_read_b64. Inner math: 3 v_pk_fma_f32 + 1 v_min3_f32
// per 2 targets per query = 2 VALU slots/pair.

#define NPTS 16384
constexpr int NQ   = 16;            // queries per wave
constexpr int NW   = 4;             // waves per block
constexpr int QPB  = NW * NQ;       // 64 queries per block
constexpr int SEG  = 4096;          // targets per LDS pass (4 x 16 KB = 64 KB)
constexpr int NBLK = NPTS / QPB;    // 256 blocks per direction

typedef float v2f __attribute__((ext_vector_type(2)));

__global__ __launch_bounds__(256, 2) void cd_main(const float* __restrict__ gt,
                                                  const float* __restrict__ gen,
                                                  float* __restrict__ part) {
    const int dir = blockIdx.y;                    // 0: gt->gen, 1: gen->gt
    const float* __restrict__ Q = dir ? gen : gt;
    const float* __restrict__ T = dir ? gt : gen;

    __shared__ float TX[SEG], TY[SEG], TZ[SEG], TW[SEG];
    __shared__ float bsum[NW];

    const int lane = threadIdx.x & 63;
    const int wave = __builtin_amdgcn_readfirstlane(threadIdx.x >> 6);

    // Wave-uniform query block: NQ queries duplicated into packed pairs.
    const int qbase = blockIdx.x * QPB + wave * NQ;
    v2f qx[NQ], qy[NQ], qz[NQ];
    #pragma unroll
    for (int i = 0; i < NQ; ++i) {
        const float x = Q[3 * (qbase + i) + 0];
        const float y = Q[3 * (qbase + i) + 1];
        const float z = Q[3 * (qbase + i) + 2];
        qx[i] = (v2f){x, x};
        qy[i] = (v2f){y, y};
        qz[i] = (v2f){z, z};
    }

    float m[NQ];
    #pragma unroll
    for (int i = 0; i < NQ; ++i) m[i] = FLT_MAX;

    for (int s = 0; s < NPTS; s += SEG) {
        // Stage + transform SEG targets into SoA LDS (stride-1 writes,
        // conflict-free; ~1.5% of runtime).
        #pragma unroll
        for (int k = 0; k < SEG / 256; ++k) {
            const int p = k * 256 + threadIdx.x;
            const float x = T[3 * (s + p) + 0];
            const float y = T[3 * (s + p) + 1];
            const float z = T[3 * (s + p) + 2];
            TX[p] = -2.0f * x;
            TY[p] = -2.0f * y;
            TZ[p] = -2.0f * z;
            TW[p] = fmaf(x, x, fmaf(y, y, z * z));
        }
        __syncthreads();

        // Sweep: each step, lane handles 2 consecutive targets vs NQ queries.
        #pragma unroll 2
        for (int st = 0; st < SEG; st += 128) {
            const int b = st + 2 * lane;
            const v2f tx = *(const v2f*)&TX[b];
            const v2f ty = *(const v2f*)&TY[b];
            const v2f tz = *(const v2f*)&TZ[b];
            const v2f tw = *(const v2f*)&TW[b];
            #pragma unroll
            for (int i = 0; i < NQ; ++i) {
                v2f d;
                asm("v_pk_fma_f32 %0, %1, %2, %3"
                    : "=v"(d) : "v"(qz[i]), "v"(tz), "v"(tw));
                asm("v_pk_fma_f32 %0, %1, %2, %0"
                    : "+v"(d) : "v"(qy[i]), "v"(ty));
                asm("v_pk_fma_f32 %0, %1, %2, %0"
                    : "+v"(d) : "v"(qx[i]), "v"(tx));
                m[i] = fminf(fminf(d.x, d.y), m[i]);   // -> v_min3_f32
            }
        }
        __syncthreads();
    }

    // Cross-lane min per query, then per-wave sum of (min + |q|^2).
    float wsum = 0.0f;
    #pragma unroll
    for (int i = 0; i < NQ; ++i) {
        float v = m[i];
        #pragma unroll
        for (int off = 32; off > 0; off >>= 1)
            v = fminf(v, __shfl_down(v, off, 64));
        const float x = qx[i].x, y = qy[i].x, z = qz[i].x;
        wsum += v + fmaf(x, x, fmaf(y, y, z * z));   // lane 0 holds true min
    }
    if (lane == 0) bsum[wave] = wsum;
    __syncthreads();
    if (threadIdx.x == 0)
        part[blockIdx.y * NBLK + blockIdx.x] = bsum[0] + bsum[1] + bsum[2] + bsum[3];
}

__global__ __launch_bounds__(512) void cd_reduce(const float* __restrict__ part,
                                                 float* __restrict__ out) {
    float v = part[threadIdx.x];                   // 512 partials, 512 threads
    #pragma unroll
    for (int off = 32; off > 0; off >>= 1) v += __shfl_down(v, off, 64);
    __shared__ float ws[8];
    const int lane = threadIdx.x & 63, w = threadIdx.x >> 6;
    if (lane == 0) ws[w] = v;
    __syncthreads();
    if (threadIdx.x == 0) {
        float s = 0.0f;
        #pragma unroll
        for (int i = 0; i < 8; ++i) s += ws[i];
        out[0] = s * (1.0f / (float)NPTS);
    }
}

extern "C" void kernel_launch(void* const* d_in, const int* in_sizes, int n_in,
                              void* d_out, int out_size, void* d_ws, size_t ws_size,
                              hipStream_t stream) {
    const float* gt  = (const float*)d_in[0];
    const float* gen = (const float*)d_in[1];
    float* part      = (float*)d_ws;               // 512 floats
    float* out       = (float*)d_out;

    dim3 grid(NBLK, 2);                            // 256 x 2 = 512 blocks
    cd_main<<<grid, 256, 0, stream>>>(gt, gen, part);
    cd_reduce<<<1, 512, 0, stream>>>(part, out);
}